// Round 11
// baseline (196.047 us; speedup 1.0000x reference)
//
#include <hip/hip_runtime.h>
#include <hip/hip_bf16.h>

#define NROW 1600
#define NEG  3200
#define ROWS_FLAT 25600
#define NSPLIT 25        // 25 x 128 = 3200 j's

using bf16x8 = __attribute__((ext_vector_type(8))) short;
using f32x4  = __attribute__((ext_vector_type(4))) float;

__device__ __forceinline__ float bf2f(unsigned v) { return __uint_as_float(v << 16); }
__device__ __forceinline__ ushort f2bf(float f) {
  __hip_bfloat16 h = __float2bfloat16(f);
  return *(ushort*)&h;
}
__device__ __forceinline__ float load1(const ushort* p, size_t idx, int f32) {
  return f32 ? ((const float*)p)[idx] : bf2f(p[idx]);
}
__device__ __forceinline__ void load8(const ushort* p, size_t idx, int f32, float* o) {
  if (f32) {
    const float* q = (const float*)p;
    float4 a = *(const float4*)(q + idx);
    float4 b = *(const float4*)(q + idx + 4);
    o[0]=a.x; o[1]=a.y; o[2]=a.z; o[3]=a.w;
    o[4]=b.x; o[5]=b.y; o[6]=b.z; o[7]=b.w;
  } else {
    uint4 u = *(const uint4*)(p + idx);
    o[0]=bf2f(u.x & 0xffffu); o[1]=bf2f(u.x >> 16);
    o[2]=bf2f(u.y & 0xffffu); o[3]=bf2f(u.y >> 16);
    o[4]=bf2f(u.z & 0xffffu); o[5]=bf2f(u.z >> 16);
    o[6]=bf2f(u.w & 0xffffu); o[7]=bf2f(u.w >> 16);
  }
}
// wave-level dtype sniff: 1 = fp32, 0 = bf16.
__device__ __forceinline__ int sniff_f32(const ushort* p, int lane) {
  unsigned e = ((unsigned)p[2*lane] >> 7) & 0xffu;
  unsigned long long b = __ballot(e >= 100u && e <= 140u);
  return (__popcll(b) >= 40) ? 0 : 1;
}

// ---------------- K0: coalesced W transpose (LDS) + zero accumulators ----------------
__global__ __launch_bounds__(256) void k_prepw(const ushort* __restrict__ W,
    ushort* __restrict__ Wt, int* __restrict__ zbase) {
  __shared__ float ld[16][257];
  if (blockIdx.x == 0 && threadIdx.x < 21) zbase[threadIdx.x] = 0;  // wsum[4]+cnt[16]+done[1]
  int fW = sniff_f32(W, threadIdx.x & 63);
  int k0 = blockIdx.x * 16, tid = threadIdx.x;
  #pragma unroll
  for (int r = 0; r < 16; r++) ld[r][tid] = load1(W, (size_t)(k0 + r)*256 + tid, fW);
  __syncthreads();
  ushort buf[16];
  #pragma unroll
  for (int r = 0; r < 16; r++) buf[r] = f2bf(ld[r][tid]);
  *(uint4*)(Wt + (size_t)tid*256 + k0)     = *(uint4*)&buf[0];
  *(uint4*)(Wt + (size_t)tid*256 + k0 + 8) = *(uint4*)&buf[8];
}

// ---------------- K1: MFMA projection + L2 normalize ----------------
// Pb layout (t-major): row R = t*3200 + srcid*1600 + b*100 + q, addr R*256+c.
__global__ __launch_bounds__(256) void k_proj(const ushort* __restrict__ fe0,
    const ushort* __restrict__ fe1, const ushort* __restrict__ Wt,
    const ushort* __restrict__ bias, ushort* __restrict__ Pb) {
  __shared__ union {
    ushort x[64*256];      // 32 KB swizzled A-tile: phys_k = k ^ ((r&7)<<3)
    ushort c[4][32*72];    // epilogue buffer
  } sh;
  __shared__ float s_ss[4][64];
  const int tid = threadIdx.x;
  const int w = tid >> 6, lane = tid & 63, q = lane >> 4, m = lane & 15;
  const int grow0 = blockIdx.x * 64;
  const int src1 = (grow0 >= ROWS_FLAT);
  const ushort* src = src1 ? fe1 : fe0;
  const size_t rbase = (size_t)(src1 ? grow0 - ROWS_FLAT : grow0) * 256;
  const int fSrc = sniff_f32(src, lane);
  const int fB   = sniff_f32(bias, lane);
  if (!fSrc) {   // bf16: async direct-to-LDS, swizzle via permuted global source
    #pragma unroll
    for (int i = 0; i < 8; i++) {
      int c = w*8 + i;
      int r = 2*c + (lane >> 5);
      int kc = (lane & 31) ^ (r & 7);
      const ushort* gp = src + rbase + (size_t)r*256 + kc*8;
      __builtin_amdgcn_global_load_lds(
        (const __attribute__((address_space(1))) unsigned int*)gp,
        (__attribute__((address_space(3))) unsigned int*)&sh.x[c*512],
        16, 0, 0);
    }
  } else {       // fp32 convert path
    #pragma unroll
    for (int i = 0; i < 8; i++) {
      int l = tid + i*256;
      int r = l >> 5, kc = l & 31;
      float o[8];
      load8(src, rbase + (size_t)r*256 + kc*8, 1, o);
      uint4 u;
      u.x = (unsigned)f2bf(o[0]) | ((unsigned)f2bf(o[1]) << 16);
      u.y = (unsigned)f2bf(o[2]) | ((unsigned)f2bf(o[3]) << 16);
      u.z = (unsigned)f2bf(o[4]) | ((unsigned)f2bf(o[5]) << 16);
      u.w = (unsigned)f2bf(o[6]) | ((unsigned)f2bf(o[7]) << 16);
      *(uint4*)&sh.x[r*256 + ((kc*8) ^ ((r&7)<<3))] = u;
    }
  }
  __syncthreads();
  f32x4 acc[4][4];
  #pragma unroll
  for (int nt = 0; nt < 4; nt++) {
    float bb = load1(bias, w*64 + nt*16 + m, fB);
    f32x4 v = {bb, bb, bb, bb};
    #pragma unroll
    for (int mt = 0; mt < 4; mt++) acc[mt][nt] = v;
  }
  const int sw = (m & 7) << 3;
  const ushort* wbase = Wt + (size_t)(w*64 + m)*256 + q*8;
  bf16x8 a_cur[4], b_cur[4];
  #pragma unroll
  for (int mt = 0; mt < 4; mt++)
    a_cur[mt] = *(const bf16x8*)&sh.x[(mt*16 + m)*256 + ((q*8) ^ sw)];
  #pragma unroll
  for (int nt = 0; nt < 4; nt++)
    b_cur[nt] = *(const bf16x8*)(wbase + (size_t)nt*16*256);
  #pragma unroll
  for (int k = 0; k < 8; k++) {
    bf16x8 a_nxt[4], b_nxt[4];
    if (k < 7) {
      int k0 = (k + 1) * 32;
      #pragma unroll
      for (int nt = 0; nt < 4; nt++)
        b_nxt[nt] = *(const bf16x8*)(wbase + (size_t)nt*16*256 + k0);
      int pk = (k0 + q*8) ^ sw;
      #pragma unroll
      for (int mt = 0; mt < 4; mt++)
        a_nxt[mt] = *(const bf16x8*)&sh.x[(mt*16 + m)*256 + pk];
    }
    #pragma unroll
    for (int nt = 0; nt < 4; nt++)
      #pragma unroll
      for (int mt = 0; mt < 4; mt++)
        acc[mt][nt] = __builtin_amdgcn_mfma_f32_16x16x32_bf16(a_cur[mt], b_cur[nt], acc[mt][nt], 0, 0, 0);
    if (k < 7) {
      #pragma unroll
      for (int x = 0; x < 4; x++) { a_cur[x] = a_nxt[x]; b_cur[x] = b_nxt[x]; }
    }
  }
  float ssp[4][4];
  #pragma unroll
  for (int mt = 0; mt < 4; mt++)
    #pragma unroll
    for (int reg = 0; reg < 4; reg++) {
      float s = 0.f;
      #pragma unroll
      for (int nt = 0; nt < 4; nt++) { float v = acc[mt][nt][reg]; s += v*v; }
      ssp[mt][reg] = s;
    }
  #pragma unroll
  for (int mk = 1; mk < 16; mk <<= 1)
    #pragma unroll
    for (int mt = 0; mt < 4; mt++)
      #pragma unroll
      for (int reg = 0; reg < 4; reg++) ssp[mt][reg] += __shfl_xor(ssp[mt][reg], mk, 64);
  if (m == 0)
    #pragma unroll
    for (int mt = 0; mt < 4; mt++)
      #pragma unroll
      for (int reg = 0; reg < 4; reg++) s_ss[w][mt*16 + 4*q + reg] = ssp[mt][reg];
  __syncthreads();
  float inv[4][4];
  #pragma unroll
  for (int mt = 0; mt < 4; mt++)
    #pragma unroll
    for (int reg = 0; reg < 4; reg++) {
      int row = mt*16 + 4*q + reg;
      float s = s_ss[0][row] + s_ss[1][row] + s_ss[2][row] + s_ss[3][row];
      inv[mt][reg] = 1.0f / sqrtf(s);
    }
  #pragma unroll
  for (int half = 0; half < 2; half++) {
    #pragma unroll
    for (int mt = half*2; mt < half*2 + 2; mt++)
      #pragma unroll
      for (int reg = 0; reg < 4; reg++) {
        int rl = (mt - half*2)*16 + 4*q + reg;
        #pragma unroll
        for (int nt = 0; nt < 4; nt++)
          sh.c[w][rl*72 + nt*16 + m] = f2bf(acc[mt][nt][reg] * inv[mt][reg]);
      }
    int rl = (lane >> 3), c16 = lane & 7;
    #pragma unroll
    for (int it = 0; it < 4; it++) {
      int row = it*8 + rl;
      int grow = grow0 + half*32 + row;
      int srcid = grow / ROWS_FLAT;
      int rem   = grow % ROWS_FLAT;
      int b  = rem / 1600;
      int t  = (rem / 100) & 15;
      int qq = rem % 100;
      size_t orow = ((size_t)t*3200 + srcid*1600 + b*100 + qq) * 256;   // t-major
      uint4 v = *(uint4*)&sh.c[w][row*72 + c16*8];
      *(uint4*)(Pb + orow + w*64 + c16*8) = v;
    }
  }
}

// ---------------- K2: bridge prep -> BUCKETED Ab_s/prm_s, numer, softplus ----------------
__global__ __launch_bounds__(256) void k_bridge(const ushort* __restrict__ Pb,
    const int* __restrict__ bridge, ushort* __restrict__ Ab_s,
    float* __restrict__ prm_s, float* __restrict__ numer,
    int* __restrict__ cnt, int* __restrict__ lst, float* __restrict__ wsum) {
  int i = blockIdx.x, c = threadIdx.x;
  int bh = bridge[i*3+0], bp = bridge[i*3+1], bt = bridge[i*3+2];
  float bhf = (float)bh, bpf = (float)bp, btf = (float)bt;
  float alpha = (bpf - bhf) / (btf - bhf);
  float sigma = alpha * (btf - bpf);
  float g0 = bf2f(Pb[((size_t)bh*3200 + i)*256 + c]);
  float g1 = bf2f(Pb[((size_t)bp*3200 + i)*256 + c]);
  float g2 = bf2f(Pb[((size_t)bt*3200 + i)*256 + c]);
  float head = bf2f(Pb[(size_t)i*256 + c]);
  float tail = bf2f(Pb[((size_t)15*3200 + i)*256 + c]);
  float a = (1.0f - alpha) * g0 + alpha * g2;
  float x = g1 - a;
  float xx = x*x, aac = a*a, sc = head*tail;
  #pragma unroll
  for (int mk = 1; mk < 64; mk <<= 1) {
    xx  += __shfl_xor(xx, mk, 64);
    aac += __shfl_xor(aac, mk, 64);
    sc  += __shfl_xor(sc, mk, 64);
  }
  __shared__ float red[3][4];
  __shared__ int s_pos;
  int wv = c >> 6;
  if ((c & 63) == 0) { red[0][wv]=xx; red[1][wv]=aac; red[2][wv]=sc; }
  __syncthreads();
  if (c == 0) {
    float XX = red[0][0]+red[0][1]+red[0][2]+red[0][3];
    float AA = red[1][0]+red[1][1]+red[1][2]+red[1][3];
    float SC = red[2][0]+red[2][1]+red[2][2]+red[2][3];
    float inv2s2 = 1.0f / (2.0f * sigma * sigma);
    numer[i] = expf(-XX * inv2s2);
    float sp = log1pf(expf(0.3f - SC));
    atomicAdd(wsum + 1, sp * (1.0f / 1600.0f));
    int pos = atomicAdd(cnt + bp, 1);
    s_pos = pos;
    lst[bp * 1600 + pos] = i;
    prm_s[(bp*1600 + pos)*2 + 0] = inv2s2;
    prm_s[(bp*1600 + pos)*2 + 1] = AA;
  }
  __syncthreads();
  Ab_s[((size_t)bp*1600 + s_pos)*256 + c] = f2bf(a);
}

// ---------------- top-5 helpers ----------------
__device__ __forceinline__ void sort5(float* c) {
  #define CE(i,j) { float hi = fmaxf(c[i], c[j]), lo = fminf(c[i], c[j]); c[i]=hi; c[j]=lo; }
  CE(0,1) CE(3,4) CE(2,4) CE(2,3) CE(1,4) CE(0,3) CE(0,2) CE(1,3) CE(1,2)
  #undef CE
}
__device__ __forceinline__ void ins5(float* t, float v) {
  float hi, lo;
  hi = fmaxf(t[0], v); lo = fminf(t[0], v); t[0] = hi; v = lo;
  hi = fmaxf(t[1], v); lo = fminf(t[1], v); t[1] = hi; v = lo;
  hi = fmaxf(t[2], v); lo = fminf(t[2], v); t[2] = hi; v = lo;
  hi = fmaxf(t[3], v); lo = fminf(t[3], v); t[3] = hi; v = lo;
  t[4] = fmaxf(t[4], v);
}

// ---------------- K3: fused dist + per-split top-5 ----------------
// 128 i's (bucketed => coalesced) x 128 j's (t-major Pb => coalesced).
__global__ __launch_bounds__(256) void k_cross(const ushort* __restrict__ Pb,
    const ushort* __restrict__ Ab_s, const float* __restrict__ prm_s,
    const int* __restrict__ cnt, const int* __restrict__ lst,
    float* __restrict__ part) {
  int t = blockIdx.z;
  int n_t = min(cnt[t], 1600);
  int i0 = blockIdx.y * 128;
  if (i0 >= n_t) return;
  int j0 = blockIdx.x * 128;
  __shared__ int s_gis[128];
  __shared__ float s_red[4][128][6];
  int tid = threadIdx.x;
  if (tid < 128) {
    int gi = lst[t*1600 + min(i0 + tid, n_t - 1)];
    s_gis[tid] = min(max(gi, 0), NROW - 1);
  }
  __syncthreads();
  const int w = tid >> 6, lane = tid & 63, q = lane >> 4, m = lane & 15;
  const ushort* jp[2];
  #pragma unroll
  for (int jt = 0; jt < 2; jt++)
    jp[jt] = Pb + ((size_t)t*3200 + j0 + w*32 + jt*16 + m)*256 + q*8;
  int irow[8];
  const ushort* ip[8];
  #pragma unroll
  for (int it = 0; it < 8; it++) {
    irow[it] = min(i0 + it*16 + m, 1599);
    ip[it] = Ab_s + ((size_t)t*1600 + irow[it])*256 + q*8;
  }
  f32x4 acc[2][8];
  #pragma unroll
  for (int jt = 0; jt < 2; jt++)
    #pragma unroll
    for (int it = 0; it < 8; it++) { f32x4 z = {0.f,0.f,0.f,0.f}; acc[jt][it] = z; }
  bf16x8 jc[2], ic[8];
  #pragma unroll
  for (int jt = 0; jt < 2; jt++) jc[jt] = *(const bf16x8*)(jp[jt]);
  #pragma unroll
  for (int it = 0; it < 8; it++) ic[it] = *(const bf16x8*)(ip[it]);
  #pragma unroll
  for (int k = 0; k < 8; k++) {
    bf16x8 jn[2], in[8];
    if (k < 7) {
      int o = (k + 1) * 32;
      #pragma unroll
      for (int jt = 0; jt < 2; jt++) jn[jt] = *(const bf16x8*)(jp[jt] + o);
      #pragma unroll
      for (int it = 0; it < 8; it++) in[it] = *(const bf16x8*)(ip[it] + o);
    }
    #pragma unroll
    for (int it = 0; it < 8; it++) {
      acc[0][it] = __builtin_amdgcn_mfma_f32_16x16x32_bf16(jc[0], ic[it], acc[0][it], 0, 0, 0);
      acc[1][it] = __builtin_amdgcn_mfma_f32_16x16x32_bf16(jc[1], ic[it], acc[1][it], 0, 0, 0);
    }
    if (k < 7) {
      jc[0] = jn[0]; jc[1] = jn[1];
      #pragma unroll
      for (int it = 0; it < 8; it++) ic[it] = in[it];
    }
  }
  // D: row(j) = jt*16 + 4q+reg, col(i) = it*16 + m
  float top[8][5], selfv[8], pi[8], pa[8];
  int gi[8];
  #pragma unroll
  for (int it = 0; it < 8; it++) {
    pi[it] = prm_s[(t*1600 + irow[it])*2];
    pa[it] = prm_s[(t*1600 + irow[it])*2 + 1];
    gi[it] = s_gis[it*16 + m];
    selfv[it] = -1e30f;
    #pragma unroll
    for (int k = 0; k < 5; k++) top[it][k] = -1e30f;
  }
  #pragma unroll
  for (int jt = 0; jt < 2; jt++)
    #pragma unroll
    for (int reg = 0; reg < 4; reg++) {
      int j = j0 + w*32 + jt*16 + 4*q + reg;
      #pragma unroll
      for (int it = 0; it < 8; it++) {
        float d = -(1.0f - 2.0f*acc[jt][it][reg] + pa[it]) * pi[it];
        if (j == gi[it]) selfv[it] = d; else ins5(top[it], d);
      }
    }
  #pragma unroll
  for (int mk = 16; mk <= 32; mk <<= 1) {
    #pragma unroll
    for (int it = 0; it < 8; it++) {
      float o[5], c[5];
      #pragma unroll
      for (int k = 0; k < 5; k++) o[k] = __shfl_xor(top[it][k], mk, 64);
      #pragma unroll
      for (int k = 0; k < 5; k++) c[k] = fmaxf(top[it][k], o[4 - k]);
      sort5(c);
      #pragma unroll
      for (int k = 0; k < 5; k++) top[it][k] = c[k];
      selfv[it] = fmaxf(selfv[it], __shfl_xor(selfv[it], mk, 64));
    }
  }
  if (q == 0) {
    #pragma unroll
    for (int it = 0; it < 8; it++) {
      #pragma unroll
      for (int k = 0; k < 5; k++) s_red[w][it*16 + m][k] = top[it][k];
      s_red[w][it*16 + m][5] = selfv[it];
    }
  }
  __syncthreads();
  if (tid < 128 && i0 + tid < n_t) {
    float T[5], S = s_red[0][tid][5];
    #pragma unroll
    for (int k = 0; k < 5; k++) T[k] = s_red[0][tid][k];
    #pragma unroll
    for (int w2 = 1; w2 < 4; w2++) {
      #pragma unroll
      for (int k = 0; k < 5; k++) ins5(T, s_red[w2][tid][k]);
      S = fmaxf(S, s_red[w2][tid][5]);
    }
    float* pp = part + ((size_t)s_gis[tid]*NSPLIT + blockIdx.x) * 6;
    #pragma unroll
    for (int k = 0; k < 5; k++) pp[k] = T[k];
    pp[5] = S;
  }
}

// ---------------- K4: parallel merge + last-block output write ----------------
__global__ __launch_bounds__(64) void k_merge(const float* __restrict__ part,
    const float* __restrict__ numer, float* __restrict__ wsum, int* __restrict__ done,
    const ushort* __restrict__ fe0, void* __restrict__ out) {
  int i = blockIdx.x * 64 + threadIdx.x;
  const float* pp = part + (size_t)i * NSPLIT * 6;
  float T[5]; float S = pp[5];
  #pragma unroll
  for (int k = 0; k < 5; k++) T[k] = pp[k];
  #pragma unroll
  for (int s = 1; s < NSPLIT; s++) {
    const float* ps = pp + s*6;
    float v0 = ps[0], v1 = ps[1], v2 = ps[2], v3 = ps[3], v4 = ps[4], v5 = ps[5];
    ins5(T, v0); ins5(T, v1); ins5(T, v2); ins5(T, v3); ins5(T, v4);
    S = fmaxf(S, v5);
  }
  float deno = expf(S);
  #pragma unroll
  for (int k = 0; k < 5; k++) deno += expf(T[k]);
  float local = numer[i] / deno;
  #pragma unroll
  for (int mk = 1; mk < 64; mk <<= 1) local += __shfl_xor(local, mk, 64);
  __shared__ int s_last;
  if (threadIdx.x == 0) {
    atomicAdd(wsum + 0, local * (1.0f / 1600.0f));
    __threadfence();
    s_last = (atomicAdd(done, 1) == 24);
  }
  __syncthreads();
  if (s_last) {
    int f = sniff_f32(fe0, threadIdx.x);
    if (threadIdx.x == 0) {
      __threadfence();
      float brown = __hip_atomic_load(wsum + 0, __ATOMIC_RELAXED, __HIP_MEMORY_SCOPE_AGENT);
      float sp    = __hip_atomic_load(wsum + 1, __ATOMIC_RELAXED, __HIP_MEMORY_SCOPE_AGENT);
      if (f) {
        ((float*)out)[0] = brown;
        ((float*)out)[1] = sp;
      } else {
        ushort* o = (ushort*)out;
        o[0] = f2bf(brown);
        o[1] = f2bf(sp);
      }
    }
  }
}

extern "C" void kernel_launch(void* const* d_in, const int* in_sizes, int n_in,
                              void* d_out, int out_size, void* d_ws, size_t ws_size,
                              hipStream_t stream) {
  const ushort* fe0    = (const ushort*)d_in[0];
  const ushort* fe1    = (const ushort*)d_in[1];
  const ushort* W      = (const ushort*)d_in[2];
  const ushort* bias   = (const ushort*)d_in[3];
  const int*    bridge = (const int*)d_in[4];

  // workspace (~41 MB)
  ushort* Pb    = (ushort*)d_ws;               // 13,107,200 (t-major)
  ushort* Ab_s  = Pb + 13107200;               // 16*1600*256 = 6,553,600 (bucketed)
  ushort* Wt    = Ab_s + 6553600;              // 65,536
  float*  part  = (float*)(Wt + 65536);        // 1600*25*6 = 240,000
  float*  prm_s = part + 240000;               // 16*1600*2 = 51,200
  float*  numer = prm_s + 51200;               // 1,600
  float*  wsum  = numer + 1600;                // 4 floats
  int*    cnt   = (int*)(wsum + 4);            // 16
  int*    done  = cnt + 16;                    // 1
  int*    lst   = done + 1;                    // 25,600

  k_prepw <<<16, 256, 0, stream>>>(W, Wt, (int*)wsum);   // also zeroes wsum/cnt/done
  k_proj  <<<800, 256, 0, stream>>>(fe0, fe1, Wt, bias, Pb);
  k_bridge<<<1600, 256, 0, stream>>>(Pb, bridge, Ab_s, prm_s, numer, cnt, lst, wsum);
  k_cross <<<dim3(NSPLIT, 13, 16), 256, 0, stream>>>(Pb, Ab_s, prm_s, cnt, lst, part);
  k_merge <<<25, 64, 0, stream>>>(part, numer, wsum, done, fe0, d_out);
}